// Round 1
// baseline (1201.434 us; speedup 1.0000x reference)
//
#include <hip/hip_runtime.h>
#include <hip/hip_bf16.h>

#define B_NUM 2
#define S_LEN 2048
#define E_DIM 1024
#define H_NUM 16
#define D_DIM 64

// ---------------------------------------------------------------------------
// GEMM: C[m][n] = sum_k A[m][k] * Bw[n][k]   (both operands K-contiguous)
// 64x64 tile, BK=16, 256 threads, 4x4 micro-tile, fp32.
// LDS tiles stored transposed [BK][64] so inner-loop reads are float4 and
// conflict-free (a-read: 4 distinct banks broadcast; b-read: 2-way, free).
// ---------------------------------------------------------------------------
__global__ __launch_bounds__(256)
void gemm_bt_f32(const float* __restrict__ A, const float* __restrict__ Bw,
                 float* __restrict__ C, int M, int N, int K) {
    __shared__ float As[16][64];
    __shared__ float Bs[16][64];
    const int tid = threadIdx.x;
    const int tx = tid & 15;        // 0..15 -> C cols tx*4..tx*4+3
    const int ty = tid >> 4;        // 0..15 -> C rows ty*4..ty*4+3
    const int bm = blockIdx.y * 64;
    const int bn = blockIdx.x * 64;
    const int lr = tid >> 2;        // 0..63 tile row to load
    const int lc = (tid & 3) * 4;   // k offset within BK

    float acc[4][4];
#pragma unroll
    for (int i = 0; i < 4; ++i)
#pragma unroll
        for (int j = 0; j < 4; ++j) acc[i][j] = 0.f;

    for (int k0 = 0; k0 < K; k0 += 16) {
        float4 av = *(const float4*)&A[(size_t)(bm + lr) * K + k0 + lc];
        float4 bv = *(const float4*)&Bw[(size_t)(bn + lr) * K + k0 + lc];
        As[lc + 0][lr] = av.x; As[lc + 1][lr] = av.y;
        As[lc + 2][lr] = av.z; As[lc + 3][lr] = av.w;
        Bs[lc + 0][lr] = bv.x; Bs[lc + 1][lr] = bv.y;
        Bs[lc + 2][lr] = bv.z; Bs[lc + 3][lr] = bv.w;
        __syncthreads();
#pragma unroll
        for (int kk = 0; kk < 16; ++kk) {
            float a[4], b[4];
            *(float4*)a = *(const float4*)&As[kk][ty * 4];
            *(float4*)b = *(const float4*)&Bs[kk][tx * 4];
#pragma unroll
            for (int i = 0; i < 4; ++i)
#pragma unroll
                for (int j = 0; j < 4; ++j) acc[i][j] += a[i] * b[j];
        }
        __syncthreads();
    }
#pragma unroll
    for (int i = 0; i < 4; ++i) {
        float4 o = make_float4(acc[i][0], acc[i][1], acc[i][2], acc[i][3]);
        *(float4*)&C[(size_t)(bm + ty * 4 + i) * N + bn + tx * 4] = o;
    }
}

// ---------------------------------------------------------------------------
// Flash attention fp32. Grid: (S/64, H, B), block 256.
// qkv layout: (B, S, 3E) with f = h*192 + {0..63:q, 64..127:k, 128..191:v}.
// Each block: 64 q-rows of one (b,h). KV tiles of 32. Online softmax.
// Thread t: rows r0=t>>3 and r0+32; cols c = (t&7) + 8j (bank-friendly);
// PV d-slice (t&7)*8.
// Output written as (B, S, E) with e = h*64+d  (i.e. values already
// transposed/merged) so the output projection is a plain GEMM.
// ---------------------------------------------------------------------------
__global__ __launch_bounds__(256)
void attn_f32(const float* __restrict__ qkv, const int* __restrict__ mask,
              float* __restrict__ vout) {
    const int q0 = blockIdx.x * 64;
    const int h  = blockIdx.y;
    const int b  = blockIdx.z;
    __shared__ float Qs[64][68];
    __shared__ float Ks[32][68];
    __shared__ float Vs[32][68];
    __shared__ float Ps[64][33];
    __shared__ int   Msk[32];

    const int tid = threadIdx.x;
    const int r0  = tid >> 3;   // 0..31 (also handles r0+32)
    const int g   = tid & 7;

    {   // load Q tile 64x64: thread -> row tid>>2, 16 floats at (tid&3)*16
        const int qr = tid >> 2;
        const int qc = (tid & 3) * 16;
        const float* src = &qkv[((size_t)(b * S_LEN + q0 + qr)) * (3 * E_DIM)
                                + h * (3 * D_DIM) + qc];
        float4 v0 = *(const float4*)&src[0];
        float4 v1 = *(const float4*)&src[4];
        float4 v2 = *(const float4*)&src[8];
        float4 v3 = *(const float4*)&src[12];
        *(float4*)&Qs[qr][qc + 0]  = v0;
        *(float4*)&Qs[qr][qc + 4]  = v1;
        *(float4*)&Qs[qr][qc + 8]  = v2;
        *(float4*)&Qs[qr][qc + 12] = v3;
    }

    float m0 = -1e30f, m1 = -1e30f, l0 = 0.f, l1 = 0.f;
    float o0[8], o1[8];
#pragma unroll
    for (int d = 0; d < 8; ++d) { o0[d] = 0.f; o1[d] = 0.f; }

    for (int k0 = 0; k0 < S_LEN; k0 += 32) {
        __syncthreads();   // prev PV reads done before overwriting Ks/Vs
        {   // load K,V tiles 32x64 each
            const int kr = tid >> 3;
            const int kc = g * 8;
            const float* kp = &qkv[((size_t)(b * S_LEN + k0 + kr)) * (3 * E_DIM)
                                   + h * (3 * D_DIM) + D_DIM + kc];
            float4 ka = *(const float4*)&kp[0];
            float4 kb = *(const float4*)&kp[4];
            float4 va = *(const float4*)&kp[D_DIM];
            float4 vb = *(const float4*)&kp[D_DIM + 4];
            *(float4*)&Ks[kr][kc]     = ka;
            *(float4*)&Ks[kr][kc + 4] = kb;
            *(float4*)&Vs[kr][kc]     = va;
            *(float4*)&Vs[kr][kc + 4] = vb;
            if (tid < 32) Msk[tid] = mask[b * S_LEN + k0 + tid];
        }
        __syncthreads();

        // ---- S = Q K^T * 0.125, cols c = g + 8j ----
        float s0[4] = {0.f, 0.f, 0.f, 0.f};
        float s1[4] = {0.f, 0.f, 0.f, 0.f};
#pragma unroll
        for (int d4 = 0; d4 < 16; ++d4) {
            float4 qa = *(const float4*)&Qs[r0][d4 * 4];
            float4 qb = *(const float4*)&Qs[r0 + 32][d4 * 4];
#pragma unroll
            for (int j = 0; j < 4; ++j) {
                float4 kv = *(const float4*)&Ks[g + 8 * j][d4 * 4];
                s0[j] += qa.x * kv.x + qa.y * kv.y + qa.z * kv.z + qa.w * kv.w;
                s1[j] += qb.x * kv.x + qb.y * kv.y + qb.z * kv.z + qb.w * kv.w;
            }
        }
        float tmax0 = -1e30f, tmax1 = -1e30f;
#pragma unroll
        for (int j = 0; j < 4; ++j) {
            const bool keep = (Msk[g + 8 * j] != 0);
            s0[j] = keep ? s0[j] * 0.125f : -1e30f;
            s1[j] = keep ? s1[j] * 0.125f : -1e30f;
            tmax0 = fmaxf(tmax0, s0[j]);
            tmax1 = fmaxf(tmax1, s1[j]);
        }
#pragma unroll
        for (int w = 1; w < 8; w <<= 1) {
            tmax0 = fmaxf(tmax0, __shfl_xor(tmax0, w));
            tmax1 = fmaxf(tmax1, __shfl_xor(tmax1, w));
        }
        const float mn0 = fmaxf(m0, tmax0);
        const float mn1 = fmaxf(m1, tmax1);
        float p0[4], p1[4], ts0 = 0.f, ts1 = 0.f;
#pragma unroll
        for (int j = 0; j < 4; ++j) {
            p0[j] = (s0[j] < -1e29f) ? 0.f : __expf(s0[j] - mn0);
            p1[j] = (s1[j] < -1e29f) ? 0.f : __expf(s1[j] - mn1);
            ts0 += p0[j]; ts1 += p1[j];
        }
#pragma unroll
        for (int w = 1; w < 8; w <<= 1) {
            ts0 += __shfl_xor(ts0, w);
            ts1 += __shfl_xor(ts1, w);
        }
        const float f0 = __expf(m0 - mn0);
        const float f1 = __expf(m1 - mn1);
        l0 = l0 * f0 + ts0;  l1 = l1 * f1 + ts1;
        m0 = mn0;            m1 = mn1;
#pragma unroll
        for (int d = 0; d < 8; ++d) { o0[d] *= f0; o1[d] *= f1; }
#pragma unroll
        for (int j = 0; j < 4; ++j) {
            Ps[r0][g + 8 * j]      = p0[j];
            Ps[r0 + 32][g + 8 * j] = p1[j];
        }
        __syncthreads();

        // ---- O += P V ----
        const int dc = g * 8;
#pragma unroll 8
        for (int c = 0; c < 32; ++c) {
            const float pa = Ps[r0][c];
            const float pb = Ps[r0 + 32][c];
            float4 va = *(const float4*)&Vs[c][dc];
            float4 vb = *(const float4*)&Vs[c][dc + 4];
            o0[0] += pa * va.x; o0[1] += pa * va.y;
            o0[2] += pa * va.z; o0[3] += pa * va.w;
            o0[4] += pa * vb.x; o0[5] += pa * vb.y;
            o0[6] += pa * vb.z; o0[7] += pa * vb.w;
            o1[0] += pb * va.x; o1[1] += pb * va.y;
            o1[2] += pb * va.z; o1[3] += pb * va.w;
            o1[4] += pb * vb.x; o1[5] += pb * vb.y;
            o1[6] += pb * vb.z; o1[7] += pb * vb.w;
        }
    }

    const float inv0 = 1.f / l0;
    const float inv1 = 1.f / l1;
    float* dst0 = &vout[((size_t)(b * S_LEN + q0 + r0)) * E_DIM + h * D_DIM + g * 8];
    float* dst1 = &vout[((size_t)(b * S_LEN + q0 + r0 + 32)) * E_DIM + h * D_DIM + g * 8];
    *(float4*)&dst0[0] = make_float4(o0[0]*inv0, o0[1]*inv0, o0[2]*inv0, o0[3]*inv0);
    *(float4*)&dst0[4] = make_float4(o0[4]*inv0, o0[5]*inv0, o0[6]*inv0, o0[7]*inv0);
    *(float4*)&dst1[0] = make_float4(o1[0]*inv1, o1[1]*inv1, o1[2]*inv1, o1[3]*inv1);
    *(float4*)&dst1[4] = make_float4(o1[4]*inv1, o1[5]*inv1, o1[6]*inv1, o1[7]*inv1);
}

// ---------------------------------------------------------------------------
extern "C" void kernel_launch(void* const* d_in, const int* in_sizes, int n_in,
                              void* d_out, int out_size, void* d_ws, size_t ws_size,
                              hipStream_t stream) {
    const float* x      = (const float*)d_in[0];
    const int*   mask   = (const int*)d_in[1];
    const float* w_qkv  = (const float*)d_in[2];
    const float* w_o    = (const float*)d_in[3];
    float*       out    = (float*)d_out;

    float* qkv  = (float*)d_ws;                                   // 4096 x 3072
    float* vbuf = qkv + (size_t)B_NUM * S_LEN * 3 * E_DIM;        // 4096 x 1024

    const int M = B_NUM * S_LEN;   // 4096
    dim3 blk(256);

    // QKV projection: (4096,1024) x (3072,1024)^T -> (4096,3072)
    gemm_bt_f32<<<dim3((3 * E_DIM) / 64, M / 64), blk, 0, stream>>>(
        x, w_qkv, qkv, M, 3 * E_DIM, E_DIM);

    // attention -> vbuf as (B,S,E)
    attn_f32<<<dim3(S_LEN / 64, H_NUM, B_NUM), blk, 0, stream>>>(qkv, mask, vbuf);

    // output projection: (4096,1024) x (1024,1024)^T -> (4096,1024)
    gemm_bt_f32<<<dim3(E_DIM / 64, M / 64), blk, 0, stream>>>(
        vbuf, w_o, out, M, E_DIM, E_DIM);
}

// Round 2
// 195.286 us; speedup vs baseline: 6.1522x; 6.1522x over previous
//
#include <hip/hip_runtime.h>
#include <hip/hip_bf16.h>

#define B_NUM 2
#define S_LEN 2048
#define E_DIM 1024
#define H_NUM 16
#define D_DIM 64
#define QKV_LD 3072

typedef __attribute__((ext_vector_type(8))) short bf16x8;
typedef __attribute__((ext_vector_type(8))) unsigned short u16x8;
typedef __attribute__((ext_vector_type(4))) unsigned short u16x4;
typedef __attribute__((ext_vector_type(4))) float f32x4;

static __device__ __forceinline__ unsigned short f2bf(float f) {
    union { float f; unsigned int u; } v; v.f = f;
    unsigned int r = v.u + 0x7fffu + ((v.u >> 16) & 1u);   // RNE
    return (unsigned short)(r >> 16);
}

// ---------------------------------------------------------------------------
// fp32 -> bf16 bulk convert (vectorized, n divisible by 4)
// ---------------------------------------------------------------------------
__global__ __launch_bounds__(256)
void cvt_f32_bf16(const float* __restrict__ in, unsigned short* __restrict__ outp, int n4) {
    int i = blockIdx.x * blockDim.x + threadIdx.x;
    if (i < n4) {
        float4 f = ((const float4*)in)[i];
        u16x4 o = { f2bf(f.x), f2bf(f.y), f2bf(f.z), f2bf(f.w) };
        ((u16x4*)outp)[i] = o;
    }
}

// ---------------------------------------------------------------------------
// bf16 MFMA GEMM: C[m][n] = sum_k A[m][k]*Bw[n][k], A/Bw bf16 (K-contig),
// C fp32 or bf16. 64x64 tile, BK=64, 4 waves, each wave 32x32 via 2x2
// 16x16x32 frags. LDS rows 128B, XOR-swizzled (byte ^= (row&7)<<4).
// QSCALE: multiply cols with (n%192)<64 by 0.125 (q columns of fused qkv).
// ---------------------------------------------------------------------------
template <bool OUT_BF16, bool QSCALE>
__global__ __launch_bounds__(256)
void gemm_bt_mfma(const unsigned short* __restrict__ A,
                  const unsigned short* __restrict__ Bw,
                  void* __restrict__ Cv, int M, int N, int K) {
    __shared__ unsigned short As[64 * 64];
    __shared__ unsigned short Bs[64 * 64];
    char* const AsB = (char*)As;
    char* const BsB = (char*)Bs;
    const int tid  = threadIdx.x;
    const int lane = tid & 63;
    const int w    = tid >> 6;
    const int lg   = lane >> 4;   // 0..3
    const int lq   = lane & 15;   // 0..15
    const int bm = blockIdx.y * 64;
    const int bn = blockIdx.x * 64;
    const int wr = (w >> 1) * 32;
    const int wc = (w & 1) * 32;
    const int sr = tid >> 2;          // staging row 0..63
    const int sc = (tid & 3) * 16;    // staging k-offset (elements)
    const int swzS = (sr & 7) << 4;

    f32x4 acc[2][2];
#pragma unroll
    for (int i = 0; i < 2; ++i)
#pragma unroll
        for (int j = 0; j < 2; ++j) acc[i][j] = (f32x4){0.f, 0.f, 0.f, 0.f};

    const unsigned short* ap = A  + (size_t)(bm + sr) * K + sc;
    const unsigned short* bp = Bw + (size_t)(bn + sr) * K + sc;

    for (int k0 = 0; k0 < K; k0 += 64) {
        __syncthreads();
        u16x8 av0 = *(const u16x8*)(ap + k0);
        u16x8 av1 = *(const u16x8*)(ap + k0 + 8);
        u16x8 bv0 = *(const u16x8*)(bp + k0);
        u16x8 bv1 = *(const u16x8*)(bp + k0 + 8);
        *(u16x8*)(AsB + sr * 128 + ((sc * 2)      ^ swzS)) = av0;
        *(u16x8*)(AsB + sr * 128 + ((sc * 2 + 16) ^ swzS)) = av1;
        *(u16x8*)(BsB + sr * 128 + ((sc * 2)      ^ swzS)) = bv0;
        *(u16x8*)(BsB + sr * 128 + ((sc * 2 + 16) ^ swzS)) = bv1;
        __syncthreads();

        bf16x8 af[2][2], bfr[2][2];
#pragma unroll
        for (int rt = 0; rt < 2; ++rt) {
            const int row = wr + rt * 16 + lq;
            const int sz = (row & 7) << 4;
            af[rt][0] = *(const bf16x8*)(AsB + row * 128 + ((lg * 16)      ^ sz));
            af[rt][1] = *(const bf16x8*)(AsB + row * 128 + ((64 + lg * 16) ^ sz));
        }
#pragma unroll
        for (int ct = 0; ct < 2; ++ct) {
            const int row = wc + ct * 16 + lq;
            const int sz = (row & 7) << 4;
            bfr[ct][0] = *(const bf16x8*)(BsB + row * 128 + ((lg * 16)      ^ sz));
            bfr[ct][1] = *(const bf16x8*)(BsB + row * 128 + ((64 + lg * 16) ^ sz));
        }
#pragma unroll
        for (int rt = 0; rt < 2; ++rt)
#pragma unroll
            for (int ct = 0; ct < 2; ++ct) {
                acc[rt][ct] = __builtin_amdgcn_mfma_f32_16x16x32_bf16(af[rt][0], bfr[ct][0], acc[rt][ct], 0, 0, 0);
                acc[rt][ct] = __builtin_amdgcn_mfma_f32_16x16x32_bf16(af[rt][1], bfr[ct][1], acc[rt][ct], 0, 0, 0);
            }
    }

#pragma unroll
    for (int rt = 0; rt < 2; ++rt)
#pragma unroll
        for (int ct = 0; ct < 2; ++ct) {
            const int row = bm + wr + rt * 16 + lg * 4;   // + r
            const int col = bn + wc + ct * 16 + lq;
            float scale = 1.f;
            if constexpr (QSCALE) scale = ((col % 192) < 64) ? 0.125f : 1.f;
#pragma unroll
            for (int r = 0; r < 4; ++r) {
                float vv = acc[rt][ct][r] * scale;
                if constexpr (OUT_BF16)
                    ((unsigned short*)Cv)[(size_t)(row + r) * N + col] = f2bf(vv);
                else
                    ((float*)Cv)[(size_t)(row + r) * N + col] = vv;
            }
        }
}

// ---------------------------------------------------------------------------
// bf16 MFMA flash attention. Grid (S/64, H, B), block 256 = 4 waves.
// Wave w: 16 q-rows (q0+w*16..+15). KV tiles of 64. qkv bf16, q pre-scaled
// by 0.125. K in LDS row-major [key][d] swizzled; V transposed [d][key]
// swizzled; P per-wave [qrow][key] bf16 swizzled. Online softmax in the
// D-frag row layout: lane owns rows lg*4+r, cols lq (+16*tile).
// Output: vout bf16 (B,S,E), e = h*64+d.
// ---------------------------------------------------------------------------
__global__ __launch_bounds__(256)
void attn_mfma(const unsigned short* __restrict__ qkv, const int* __restrict__ mask,
               unsigned short* __restrict__ vout) {
    __shared__ unsigned short Ks[64 * 64];
    __shared__ unsigned short Vt[64 * 64];
    __shared__ unsigned short Pl[4][16 * 64];
    __shared__ int Msk[64];
    char* const KsB = (char*)Ks;
    char* const VtB = (char*)Vt;

    const int tid  = threadIdx.x;
    const int lane = tid & 63;
    const int w    = tid >> 6;
    const int lg   = lane >> 4;
    const int lq   = lane & 15;
    const int q0 = blockIdx.x * 64;
    const int h  = blockIdx.y;
    const int b  = blockIdx.z;
    const size_t baseBH = (size_t)b * S_LEN * QKV_LD + (size_t)h * (3 * D_DIM);
    char* const PlB = (char*)Pl[w];

    // Q fragments in registers (reused all tiles); q pre-scaled by 0.125
    bf16x8 qf[2];
    {
        const unsigned short* qp = qkv + baseBH + (size_t)(q0 + w * 16 + lq) * QKV_LD + lg * 8;
        qf[0] = *(const bf16x8*)(qp);
        qf[1] = *(const bf16x8*)(qp + 32);
    }

    f32x4 accO[4];
#pragma unroll
    for (int dt = 0; dt < 4; ++dt) accO[dt] = (f32x4){0.f, 0.f, 0.f, 0.f};
    float mrun[4] = {-1e30f, -1e30f, -1e30f, -1e30f};
    float lrow[4] = {0.f, 0.f, 0.f, 0.f};

    const int ksr = tid >> 2;          // K staging: key row 0..63
    const int ksc = (tid & 3) * 16;    // d offset
    const int vkb = (tid & 15) * 4;    // V staging: key base
    const int vdb = (tid >> 4) * 4;    // V staging: d base 0..60

    for (int kv0 = 0; kv0 < S_LEN; kv0 += 64) {
        __syncthreads();               // prev tile's reads of Ks/Vt done
        {   // stage K [key][d], swizzled
            const unsigned short* kp = qkv + baseBH + (size_t)(kv0 + ksr) * QKV_LD + D_DIM + ksc;
            u16x8 k0v = *(const u16x8*)kp;
            u16x8 k1v = *(const u16x8*)(kp + 8);
            const int swz = (ksr & 7) << 4;
            *(u16x8*)(KsB + ksr * 128 + ((ksc * 2)      ^ swz)) = k0v;
            *(u16x8*)(KsB + ksr * 128 + ((ksc * 2 + 16) ^ swz)) = k1v;
        }
        {   // stage V transposed [d][key], swizzled
            u16x4 vr[4];
#pragma unroll
            for (int i = 0; i < 4; ++i)
                vr[i] = *(const u16x4*)(qkv + baseBH + (size_t)(kv0 + vkb + i) * QKV_LD + 2 * D_DIM + vdb);
#pragma unroll
            for (int j = 0; j < 4; ++j) {
                u16x4 o = { vr[0][j], vr[1][j], vr[2][j], vr[3][j] };
                const int row = vdb + j;
                *(u16x4*)(VtB + row * 128 + ((vkb * 2) ^ ((row & 7) << 4))) = o;
            }
        }
        if (tid < 64) Msk[tid] = mask[b * S_LEN + kv0 + tid];
        __syncthreads();

        // ---- S = Q K^T (q pre-scaled) ----
        f32x4 s[4];
#pragma unroll
        for (int ct = 0; ct < 4; ++ct) {
            const int key = ct * 16 + lq;
            const int sz = (key & 7) << 4;
            bf16x8 kb0 = *(const bf16x8*)(KsB + key * 128 + ((lg * 16)      ^ sz));
            bf16x8 kb1 = *(const bf16x8*)(KsB + key * 128 + ((64 + lg * 16) ^ sz));
            f32x4 z = (f32x4){0.f, 0.f, 0.f, 0.f};
            z = __builtin_amdgcn_mfma_f32_16x16x32_bf16(qf[0], kb0, z, 0, 0, 0);
            s[ct] = __builtin_amdgcn_mfma_f32_16x16x32_bf16(qf[1], kb1, z, 0, 0, 0);
        }

        // ---- mask + online softmax (rows lg*4+r, cols lq+16*ct) ----
        int keep[4];
#pragma unroll
        for (int ct = 0; ct < 4; ++ct) keep[ct] = Msk[ct * 16 + lq];
        float tm[4] = {-1e30f, -1e30f, -1e30f, -1e30f};
#pragma unroll
        for (int ct = 0; ct < 4; ++ct)
#pragma unroll
            for (int r = 0; r < 4; ++r) {
                float sv = keep[ct] ? s[ct][r] : -1e30f;
                s[ct][r] = sv;
                tm[r] = fmaxf(tm[r], sv);
            }
#pragma unroll
        for (int off = 1; off < 16; off <<= 1)
#pragma unroll
            for (int r = 0; r < 4; ++r) tm[r] = fmaxf(tm[r], __shfl_xor(tm[r], off));
        float fsc[4];
#pragma unroll
        for (int r = 0; r < 4; ++r) {
            float nm = fmaxf(mrun[r], tm[r]);
            fsc[r] = __expf(mrun[r] - nm);
            mrun[r] = nm;
        }
        float rs[4] = {0.f, 0.f, 0.f, 0.f};
        unsigned short pb[4][4];
#pragma unroll
        for (int ct = 0; ct < 4; ++ct)
#pragma unroll
            for (int r = 0; r < 4; ++r) {
                float p = keep[ct] ? __expf(s[ct][r] - mrun[r]) : 0.f;
                rs[r] += p;
                pb[ct][r] = f2bf(p);
            }
#pragma unroll
        for (int off = 1; off < 16; off <<= 1)
#pragma unroll
            for (int r = 0; r < 4; ++r) rs[r] += __shfl_xor(rs[r], off);
#pragma unroll
        for (int r = 0; r < 4; ++r) lrow[r] = lrow[r] * fsc[r] + rs[r];
#pragma unroll
        for (int dt = 0; dt < 4; ++dt)
#pragma unroll
            for (int r = 0; r < 4; ++r) accO[dt][r] *= fsc[r];

        // ---- write P (per-wave region, swizzled), read back as A-frags ----
#pragma unroll
        for (int ct = 0; ct < 4; ++ct)
#pragma unroll
            for (int r = 0; r < 4; ++r) {
                const int row = lg * 4 + r;
                *(unsigned short*)(PlB + row * 128 + ((((ct * 16 + lq) * 2)) ^ ((row & 7) << 4))) = pb[ct][r];
            }
        const int psz = (lq & 7) << 4;
        bf16x8 pa0 = *(const bf16x8*)(PlB + lq * 128 + ((lg * 16)      ^ psz));
        bf16x8 pa1 = *(const bf16x8*)(PlB + lq * 128 + ((64 + lg * 16) ^ psz));

        // ---- O += P V ----
#pragma unroll
        for (int dt = 0; dt < 4; ++dt) {
            const int drow = dt * 16 + lq;
            const int sz = (drow & 7) << 4;
            bf16x8 vb0 = *(const bf16x8*)(VtB + drow * 128 + ((lg * 16)      ^ sz));
            bf16x8 vb1 = *(const bf16x8*)(VtB + drow * 128 + ((64 + lg * 16) ^ sz));
            accO[dt] = __builtin_amdgcn_mfma_f32_16x16x32_bf16(pa0, vb0, accO[dt], 0, 0, 0);
            accO[dt] = __builtin_amdgcn_mfma_f32_16x16x32_bf16(pa1, vb1, accO[dt], 0, 0, 0);
        }
    }

    // ---- epilogue: normalize, store bf16 (B,S,E) ----
#pragma unroll
    for (int r = 0; r < 4; ++r) {
        const float inv = 1.f / lrow[r];
        const int qrow = q0 + w * 16 + lg * 4 + r;
        unsigned short* op = vout + (size_t)(b * S_LEN + qrow) * E_DIM + h * D_DIM;
#pragma unroll
        for (int dt = 0; dt < 4; ++dt)
            op[dt * 16 + lq] = f2bf(accO[dt][r] * inv);
    }
}

// ---------------------------------------------------------------------------
extern "C" void kernel_launch(void* const* d_in, const int* in_sizes, int n_in,
                              void* d_out, int out_size, void* d_ws, size_t ws_size,
                              hipStream_t stream) {
    const float* x      = (const float*)d_in[0];
    const int*   mask   = (const int*)d_in[1];
    const float* w_qkv  = (const float*)d_in[2];
    const float* w_o    = (const float*)d_in[3];
    float*       out    = (float*)d_out;

    const int M = B_NUM * S_LEN;     // 4096
    unsigned short* qkvb = (unsigned short*)d_ws;                    // M x 3E
    unsigned short* vbuf = qkvb + (size_t)M * 3 * E_DIM;             // M x E
    unsigned short* xb   = vbuf + (size_t)M * E_DIM;                 // M x E
    unsigned short* wqb  = xb   + (size_t)M * E_DIM;                 // 3E x E
    unsigned short* wob  = wqb  + (size_t)3 * E_DIM * E_DIM;         // E x E

    dim3 blk(256);
    {
        int n4;
        n4 = M * E_DIM / 4;
        cvt_f32_bf16<<<dim3((n4 + 255) / 256), blk, 0, stream>>>(x, xb, n4);
        n4 = 3 * E_DIM * E_DIM / 4;
        cvt_f32_bf16<<<dim3((n4 + 255) / 256), blk, 0, stream>>>(w_qkv, wqb, n4);
        n4 = E_DIM * E_DIM / 4;
        cvt_f32_bf16<<<dim3((n4 + 255) / 256), blk, 0, stream>>>(w_o, wob, n4);
    }

    // QKV projection (q columns pre-scaled by 0.125), bf16 out
    gemm_bt_mfma<true, true><<<dim3(3 * E_DIM / 64, M / 64), blk, 0, stream>>>(
        xb, wqb, qkvb, M, 3 * E_DIM, E_DIM);

    // flash attention
    attn_mfma<<<dim3(S_LEN / 64, H_NUM, B_NUM), blk, 0, stream>>>(qkvb, mask, vbuf);

    // output projection, fp32 out
    gemm_bt_mfma<false, false><<<dim3(E_DIM / 64, M / 64), blk, 0, stream>>>(
        vbuf, wob, out, M, E_DIM, E_DIM);
}

// Round 3
// 149.687 us; speedup vs baseline: 8.0263x; 1.3046x over previous
//
#include <hip/hip_runtime.h>
#include <hip/hip_bf16.h>

#define B_NUM 2
#define S_LEN 2048
#define E_DIM 1024
#define H_NUM 16
#define D_DIM 64
#define QKV_LD 3072

typedef __attribute__((ext_vector_type(8))) short bf16x8;
typedef __attribute__((ext_vector_type(8))) unsigned short u16x8;
typedef __attribute__((ext_vector_type(4))) unsigned short u16x4;
typedef __attribute__((ext_vector_type(4))) float f32x4;
typedef __attribute__((ext_vector_type(16))) float f32x16;
typedef __attribute__((ext_vector_type(2))) int i32x2;

static __device__ __forceinline__ unsigned short f2bf(float f) {
    union { float f; unsigned int u; } v; v.f = f;
    unsigned int r = v.u + 0x7fffu + ((v.u >> 16) & 1u);   // RNE
    return (unsigned short)(r >> 16);
}

static __device__ __forceinline__ unsigned cvtpk_bf16(float lo, float hi) {
    unsigned r;
    asm("v_cvt_pk_bf16_f32 %0, %1, %2" : "=v"(r) : "v"(lo), "v"(hi));
    return r;
}

// ---------------------------------------------------------------------------
// fp32 -> bf16 bulk convert
// ---------------------------------------------------------------------------
__global__ __launch_bounds__(256)
void cvt_f32_bf16(const float* __restrict__ in, unsigned short* __restrict__ outp, int n4) {
    int i = blockIdx.x * blockDim.x + threadIdx.x;
    if (i < n4) {
        float4 f = ((const float4*)in)[i];
        u16x4 o = { f2bf(f.x), f2bf(f.y), f2bf(f.z), f2bf(f.w) };
        ((u16x4*)outp)[i] = o;
    }
}

// ---------------------------------------------------------------------------
// bf16 MFMA GEMM (unchanged from round 2, known-good):
// C[m][n] = sum_k A[m][k]*Bw[n][k]; 64x64 tile, BK=64, 4 waves, 2x2 16x16x32.
// ---------------------------------------------------------------------------
template <bool OUT_BF16, bool QSCALE>
__global__ __launch_bounds__(256)
void gemm_bt_mfma(const unsigned short* __restrict__ A,
                  const unsigned short* __restrict__ Bw,
                  void* __restrict__ Cv, int M, int N, int K) {
    __shared__ unsigned short As[64 * 64];
    __shared__ unsigned short Bs[64 * 64];
    char* const AsB = (char*)As;
    char* const BsB = (char*)Bs;
    const int tid  = threadIdx.x;
    const int lane = tid & 63;
    const int w    = tid >> 6;
    const int lg   = lane >> 4;
    const int lq   = lane & 15;
    const int bm = blockIdx.y * 64;
    const int bn = blockIdx.x * 64;
    const int wr = (w >> 1) * 32;
    const int wc = (w & 1) * 32;
    const int sr = tid >> 2;
    const int sc = (tid & 3) * 16;
    const int swzS = (sr & 7) << 4;

    f32x4 acc[2][2];
#pragma unroll
    for (int i = 0; i < 2; ++i)
#pragma unroll
        for (int j = 0; j < 2; ++j) acc[i][j] = (f32x4){0.f, 0.f, 0.f, 0.f};

    const unsigned short* ap = A  + (size_t)(bm + sr) * K + sc;
    const unsigned short* bp = Bw + (size_t)(bn + sr) * K + sc;

    for (int k0 = 0; k0 < K; k0 += 64) {
        __syncthreads();
        u16x8 av0 = *(const u16x8*)(ap + k0);
        u16x8 av1 = *(const u16x8*)(ap + k0 + 8);
        u16x8 bv0 = *(const u16x8*)(bp + k0);
        u16x8 bv1 = *(const u16x8*)(bp + k0 + 8);
        *(u16x8*)(AsB + sr * 128 + ((sc * 2)      ^ swzS)) = av0;
        *(u16x8*)(AsB + sr * 128 + ((sc * 2 + 16) ^ swzS)) = av1;
        *(u16x8*)(BsB + sr * 128 + ((sc * 2)      ^ swzS)) = bv0;
        *(u16x8*)(BsB + sr * 128 + ((sc * 2 + 16) ^ swzS)) = bv1;
        __syncthreads();

        bf16x8 af[2][2], bfr[2][2];
#pragma unroll
        for (int rt = 0; rt < 2; ++rt) {
            const int row = wr + rt * 16 + lq;
            const int sz = (row & 7) << 4;
            af[rt][0] = *(const bf16x8*)(AsB + row * 128 + ((lg * 16)      ^ sz));
            af[rt][1] = *(const bf16x8*)(AsB + row * 128 + ((64 + lg * 16) ^ sz));
        }
#pragma unroll
        for (int ct = 0; ct < 2; ++ct) {
            const int row = wc + ct * 16 + lq;
            const int sz = (row & 7) << 4;
            bfr[ct][0] = *(const bf16x8*)(BsB + row * 128 + ((lg * 16)      ^ sz));
            bfr[ct][1] = *(const bf16x8*)(BsB + row * 128 + ((64 + lg * 16) ^ sz));
        }
#pragma unroll
        for (int rt = 0; rt < 2; ++rt)
#pragma unroll
            for (int ct = 0; ct < 2; ++ct) {
                acc[rt][ct] = __builtin_amdgcn_mfma_f32_16x16x32_bf16(af[rt][0], bfr[ct][0], acc[rt][ct], 0, 0, 0);
                acc[rt][ct] = __builtin_amdgcn_mfma_f32_16x16x32_bf16(af[rt][1], bfr[ct][1], acc[rt][ct], 0, 0, 0);
            }
    }

#pragma unroll
    for (int rt = 0; rt < 2; ++rt)
#pragma unroll
        for (int ct = 0; ct < 2; ++ct) {
            const int row = bm + wr + rt * 16 + lg * 4;
            const int col = bn + wc + ct * 16 + lq;
            float scale = 1.f;
            if constexpr (QSCALE) scale = ((col % 192) < 64) ? 0.125f : 1.f;
#pragma unroll
            for (int r = 0; r < 4; ++r) {
                float vv = acc[rt][ct][r] * scale;
                if constexpr (OUT_BF16)
                    ((unsigned short*)Cv)[(size_t)(row + r) * N + col] = f2bf(vv);
                else
                    ((float*)Cv)[(size_t)(row + r) * N + col] = vv;
            }
        }
}

// ---------------------------------------------------------------------------
// Flash attention, swapped-QK^T 32x32x16 structure (m214-style).
// Grid (S/128, H, B), block 256 = 4 waves, 32 q-rows/wave.
// Lane owns q-row = lane&31 (lane and lane+32 are partners holding different
// key/d halves). S^T = mfma(K, Q) + mask-bias-in-acc; softmax in-register
// (per-lane + one permlane32_swap); P assembled in-register via
// v_cvt_pk_bf16_f32 + permlane32_swap; O^T = mfma(V^T, P^T) so softmax
// state stays per-lane scalar. K and V^T staged in LDS, XOR-swizzled.
// ---------------------------------------------------------------------------
__global__ __launch_bounds__(256)
void attn_mfma32(const unsigned short* __restrict__ qkv, const int* __restrict__ mask,
                 unsigned short* __restrict__ vout) {
    __shared__ unsigned short Ks[64 * 64];
    __shared__ unsigned short Vt[64 * 64];
    __shared__ __align__(16) float MskF[64];
    char* const KsB = (char*)Ks;
    char* const VtB = (char*)Vt;

    const int tid  = threadIdx.x;
    const int lane = tid & 63;
    const int w    = tid >> 6;
    const int ln   = lane & 31;
    const int hi   = lane >> 5;
    const int q0 = blockIdx.x * 128;
    const int h  = blockIdx.y;
    const int b  = blockIdx.z;
    const size_t baseBH = (size_t)b * S_LEN * QKV_LD + (size_t)h * (3 * D_DIM);

    // Q as B-frags (pre-scaled by 0.125): qf[kk] holds Q[q=ln][d=kk*16+hi*8+j]
    bf16x8 qf[4];
    {
        const unsigned short* qp = qkv + baseBH + (size_t)(q0 + w * 32 + ln) * QKV_LD + hi * 8;
#pragma unroll
        for (int kk = 0; kk < 4; ++kk)
            qf[kk] = *(const bf16x8*)(qp + kk * 16);
    }

    f32x16 accO[2];
#pragma unroll
    for (int dt = 0; dt < 2; ++dt)
#pragma unroll
        for (int r = 0; r < 16; ++r) accO[dt][r] = 0.f;
    float mrun = 0.f, lrow = 0.f;   // m>=0 always; masked bias -3e4 -> p==0

    const int ksr = tid >> 2;          // K staging row (key)
    const int ksc = (tid & 3) * 16;    // K staging d-offset
    const int vkb = (tid & 15) * 4;    // V staging key base
    const int vdb = (tid >> 4) * 4;    // V staging d base

    for (int kv0 = 0; kv0 < S_LEN; kv0 += 64) {
        __syncthreads();
        {   // stage K [key][d], swizzled
            const unsigned short* kp = qkv + baseBH + (size_t)(kv0 + ksr) * QKV_LD + D_DIM + ksc;
            u16x8 a0 = *(const u16x8*)kp;
            u16x8 a1 = *(const u16x8*)(kp + 8);
            const int swz = (ksr & 7) << 4;
            *(u16x8*)(KsB + ksr * 128 + ((ksc * 2)      ^ swz)) = a0;
            *(u16x8*)(KsB + ksr * 128 + ((ksc * 2 + 16) ^ swz)) = a1;
        }
        {   // stage V transposed [d][key], swizzled
            u16x4 vr[4];
#pragma unroll
            for (int i = 0; i < 4; ++i)
                vr[i] = *(const u16x4*)(qkv + baseBH + (size_t)(kv0 + vkb + i) * QKV_LD + 2 * D_DIM + vdb);
#pragma unroll
            for (int j = 0; j < 4; ++j) {
                u16x4 o = { vr[0][j], vr[1][j], vr[2][j], vr[3][j] };
                const int row = vdb + j;
                *(u16x4*)(VtB + row * 128 + ((vkb * 2) ^ ((row & 7) << 4))) = o;
            }
        }
        if (tid < 64) MskF[tid] = (mask[b * S_LEN + kv0 + tid] != 0) ? 0.f : -30000.f;
        __syncthreads();

        // ---- S^T = K Q^T + bias. s[ks][reg]: key = (reg&3)+8*(reg>>2)+4*hi+32*ks, q = ln
        f32x16 s[2];
#pragma unroll
        for (int ks = 0; ks < 2; ++ks)
#pragma unroll
            for (int m = 0; m < 4; ++m) {
                f32x4 b4 = *(const f32x4*)(MskF + ks * 32 + m * 8 + hi * 4);
#pragma unroll
                for (int i = 0; i < 4; ++i) s[ks][m * 4 + i] = b4[i];
            }
#pragma unroll
        for (int ks = 0; ks < 2; ++ks) {
            const int krow = ks * 32 + ln;
            const int swz = (ln & 7) << 4;
#pragma unroll
            for (int kk = 0; kk < 4; ++kk) {
                bf16x8 kf = *(const bf16x8*)(KsB + krow * 128 + (((kk * 16 + hi * 8) * 2) ^ swz));
                s[ks] = __builtin_amdgcn_mfma_f32_32x32x16_bf16(kf, qf[kk], s[ks], 0, 0, 0);
            }
        }

        // ---- online softmax: in-lane reduce + partner exchange ----
        float tm = -3.4e38f;
#pragma unroll
        for (int ks = 0; ks < 2; ++ks)
#pragma unroll
            for (int r = 0; r < 16; ++r) tm = fmaxf(tm, s[ks][r]);
        {
            i32x2 rr = __builtin_amdgcn_permlane32_swap(__float_as_int(tm), __float_as_int(tm), false, false);
            tm = fmaxf(__int_as_float(rr[0]), __int_as_float(rr[1]));
        }
        const float mnew = fmaxf(mrun, tm);
        const float fsc = __expf(mrun - mnew);
        mrun = mnew;
        float rsum = 0.f;
#pragma unroll
        for (int ks = 0; ks < 2; ++ks)
#pragma unroll
            for (int r = 0; r < 16; ++r) {
                float p = __expf(s[ks][r] - mnew);
                s[ks][r] = p;
                rsum += p;
            }
        {
            i32x2 rr = __builtin_amdgcn_permlane32_swap(__float_as_int(rsum), __float_as_int(rsum), false, false);
            rsum = __int_as_float(rr[0]) + __int_as_float(rr[1]);
        }
        lrow = lrow * fsc + rsum;
#pragma unroll
        for (int dt = 0; dt < 2; ++dt)
#pragma unroll
            for (int r = 0; r < 16; ++r) accO[dt][r] *= fsc;

        // ---- assemble P^T B-frags in-register: pb[n] keys 16n+8*hi+j, q=ln ----
        bf16x8 pb[4];
#pragma unroll
        for (int ks = 0; ks < 2; ++ks) {
            unsigned wA[4], wB[4];
#pragma unroll
            for (int m = 0; m < 4; ++m) {
                wA[m] = cvtpk_bf16(s[ks][4 * m + 0], s[ks][4 * m + 1]);
                wB[m] = cvtpk_bf16(s[ks][4 * m + 2], s[ks][4 * m + 3]);
            }
#pragma unroll
            for (int t = 0; t < 2; ++t) {
                i32x2 ra = __builtin_amdgcn_permlane32_swap((int)wA[2 * t], (int)wA[2 * t + 1], false, false);
                i32x2 rb = __builtin_amdgcn_permlane32_swap((int)wB[2 * t], (int)wB[2 * t + 1], false, false);
                union { unsigned u[4]; bf16x8 v; } uu;
                uu.u[0] = (unsigned)ra[0];
                uu.u[1] = (unsigned)rb[0];
                uu.u[2] = (unsigned)ra[1];
                uu.u[3] = (unsigned)rb[1];
                pb[ks * 2 + t] = uu.v;
            }
        }

        // ---- O^T += V^T P^T : accO[dt][reg] = O[d=crow+32dt][q=ln] ----
#pragma unroll
        for (int dt = 0; dt < 2; ++dt) {
            const int drow = dt * 32 + ln;
            const int swz = (ln & 7) << 4;
#pragma unroll
            for (int n = 0; n < 4; ++n) {
                bf16x8 va = *(const bf16x8*)(VtB + drow * 128 + (((n * 16 + hi * 8) * 2) ^ swz));
                accO[dt] = __builtin_amdgcn_mfma_f32_32x32x16_bf16(va, pb[n], accO[dt], 0, 0, 0);
            }
        }
    }

    // ---- epilogue: normalize, store bf16 (B,S,E); d = i+8m+4hi+32dt ----
    const float inv = 1.f / lrow;
    unsigned short* op = vout + (size_t)(b * S_LEN + q0 + w * 32 + ln) * E_DIM + h * D_DIM;
#pragma unroll
    for (int dt = 0; dt < 2; ++dt)
#pragma unroll
        for (int m = 0; m < 4; ++m) {
            u16x4 o;
#pragma unroll
            for (int i = 0; i < 4; ++i) o[i] = f2bf(accO[dt][4 * m + i] * inv);
            *(u16x4*)(op + dt * 32 + m * 8 + hi * 4) = o;
        }
}

// ---------------------------------------------------------------------------
extern "C" void kernel_launch(void* const* d_in, const int* in_sizes, int n_in,
                              void* d_out, int out_size, void* d_ws, size_t ws_size,
                              hipStream_t stream) {
    const float* x      = (const float*)d_in[0];
    const int*   mask   = (const int*)d_in[1];
    const float* w_qkv  = (const float*)d_in[2];
    const float* w_o    = (const float*)d_in[3];
    float*       out    = (float*)d_out;

    const int M = B_NUM * S_LEN;     // 4096
    unsigned short* qkvb = (unsigned short*)d_ws;                    // M x 3E
    unsigned short* vbuf = qkvb + (size_t)M * 3 * E_DIM;             // M x E
    unsigned short* xb   = vbuf + (size_t)M * E_DIM;                 // M x E
    unsigned short* wqb  = xb   + (size_t)M * E_DIM;                 // 3E x E
    unsigned short* wob  = wqb  + (size_t)3 * E_DIM * E_DIM;         // E x E

    dim3 blk(256);
    {
        int n4;
        n4 = M * E_DIM / 4;
        cvt_f32_bf16<<<dim3((n4 + 255) / 256), blk, 0, stream>>>(x, xb, n4);
        n4 = 3 * E_DIM * E_DIM / 4;
        cvt_f32_bf16<<<dim3((n4 + 255) / 256), blk, 0, stream>>>(w_qkv, wqb, n4);
        n4 = E_DIM * E_DIM / 4;
        cvt_f32_bf16<<<dim3((n4 + 255) / 256), blk, 0, stream>>>(w_o, wob, n4);
    }

    // QKV projection (q columns pre-scaled by 0.125), bf16 out
    gemm_bt_mfma<true, true><<<dim3(3 * E_DIM / 64, M / 64), blk, 0, stream>>>(
        xb, wqb, qkvb, M, 3 * E_DIM, E_DIM);

    // flash attention (swapped-QK^T 32x32 structure)
    attn_mfma32<<<dim3(S_LEN / 128, H_NUM, B_NUM), blk, 0, stream>>>(qkvb, mask, vbuf);

    // output projection, fp32 out
    gemm_bt_mfma<false, false><<<dim3(E_DIM / 64, M / 64), blk, 0, stream>>>(
        vbuf, wob, out, M, E_DIM, E_DIM);
}